// Round 9
// baseline (206.169 us; speedup 1.0000x reference)
//
#include <hip/hip_runtime.h>
#include <cstdint>
#include <cstddef>

#define L_SEQ 2048
#define E_DIM 512
#define WIN 64
#define SCALE_QK 0.044194173824159216f  // 1/sqrt(512)

#define NBLK 512
#define NTHR 256

typedef __attribute__((ext_vector_type(8))) short short8;
typedef __attribute__((ext_vector_type(4))) float floatx4;

__device__ __forceinline__ unsigned short f2bf(float f) {
    unsigned int u = __float_as_uint(f);
    u += 0x7FFFu + ((u >> 16) & 1u);
    return (unsigned short)(u >> 16);
}

// software grid barrier: device-scope atomic counter + release/acquire fences.
// All NBLK blocks are co-resident (launch_bounds(256,2) => 2 blocks/CU => 512
// capacity), so arrival is guaranteed; spin is BOUNDED so a residency failure
// produces a wrong answer (diagnosable) instead of a hang.
__device__ __forceinline__ void gbar(unsigned int* cnt, unsigned int target) {
    __syncthreads();
    if (threadIdx.x == 0) {
        __threadfence();   // release: make this block's writes device-visible
        __hip_atomic_fetch_add(cnt, 1u, __ATOMIC_ACQ_REL, __HIP_MEMORY_SCOPE_AGENT);
        unsigned int v = __hip_atomic_load(cnt, __ATOMIC_ACQUIRE, __HIP_MEMORY_SCOPE_AGENT);
        for (int it = 0; it < 4000000 && v < target; ++it) {   // ~0.9 s cap
            __builtin_amdgcn_s_sleep(8);
            v = __hip_atomic_load(cnt, __ATOMIC_ACQUIRE, __HIP_MEMORY_SCOPE_AGENT);
        }
        __threadfence();   // acquire: invalidate stale cached lines for the CU
    }
    __syncthreads();
}

// ============================================================================
// ONE kernel, 512 blocks x 256 threads, plain launch (graph-capturable —
// R5's cooperative launch silently failed under capture: absmax == max|ref|
// means the output stayed zero).  Phases: A cvt -> gbar -> B qkv (bf16, fast
// R3 path, z-loop) -> gbar -> C attn (4-wave, (Qt,b,E-half) jobs).
// Replaces 4 dispatches with 2 (memset+mega): saves ~20 us of measured ~10 us
// per-dispatch boundary overhead while keeping the bf16-staged qkv speed.
// ============================================================================
#define ALD 72    // qkv LDS row stride (bf16)
#define SLD 164   // attn S-tile row stride (fp32)
__global__ __launch_bounds__(256, 2) void mega(
    const float* __restrict__ x,
    const float* __restrict__ Wq, const float* __restrict__ bq,
    const float* __restrict__ Wk, const float* __restrict__ bk,
    const float* __restrict__ Wv, const float* __restrict__ bv,
    float* __restrict__ out,
    unsigned short* __restrict__ xb, unsigned short* __restrict__ wb,
    unsigned short* __restrict__ qb, unsigned short* __restrict__ kb,
    unsigned short* __restrict__ vt, unsigned int* __restrict__ cnt)
{
    __shared__ __align__(16) char lds_raw[36864];   // B: 36.9 KB; C: 10.5 KB (2 blocks/CU OK)

    const int t   = threadIdx.x;
    const int bid = blockIdx.x;

    // ===================== Phase A: fp32 -> bf16 (validated cvt, grid-stride) ==
    for (long i = (long)bid * NTHR + t; i < 720896; i += (long)NBLK * NTHR) {
        const float* src; unsigned short* dst; long off;
        if (i < 524288) {
            src = x; dst = xb; off = i;
        } else {
            long j = i - 524288;
            int wsel = (int)(j >> 16);
            off = j & 65535;
            src = (wsel == 0) ? Wq : ((wsel == 1) ? Wk : Wv);
            dst = wb + (long)wsel * 262144;
        }
        float4 f = ((const float4*)src)[off];
        ushort4 o;
        o.x = f2bf(f.x); o.y = f2bf(f.y); o.z = f2bf(f.z); o.w = f2bf(f.w);
        ((ushort4*)dst)[off] = o;
    }
    gbar(cnt, NBLK);

    // ===================== Phase B: QKV projection (bf16, z-loop) ==============
    // 512 jobs = (64 mt, 8 nt); bid = mt + 64*nt => bid%8 = mt%8: each XCD owns
    // an m-stripe (x rows + all W L2-resident).  A staged once per kt, reused
    // across z; acc[3][2][2] fully unrolled (static indexing).
    {
        const int mt = bid & 63, nt = bid >> 6;
        const int m0 = mt * 64, n0 = nt * 64;

        unsigned short* As = (unsigned short*)lds_raw;          // [64][ALD]
        unsigned short* Bs = As + 64 * ALD;                     // [3][64][ALD]

        const int w = t >> 6, l = t & 63;
        const int wm = (w >> 1) * 32, wn = (w & 1) * 32;
        const int fr = l & 15, fq = l >> 4, fk = fq * 8;

        const int srow = t >> 2, scol = (t & 3) * 16;
        const unsigned short* gA = xb + (size_t)(m0 + srow) * 512 + scol;
        const unsigned short* gB = wb + (size_t)(n0 + srow) * 512 + scol;

        float bv_[3][2];
        {
            const float* bs[3] = { bq, bk, bv };
#pragma unroll
            for (int z = 0; z < 3; z++)
#pragma unroll
                for (int j = 0; j < 2; j++) bv_[z][j] = bs[z][n0 + wn + j * 16 + fr];
        }

        floatx4 acc[3][2][2] = {};

        for (int kt = 0; kt < 8; kt++) {
            const int kk = kt * 64;
            *(uint4*)&As[srow * ALD + scol]     = *(const uint4*)(gA + kk);
            *(uint4*)&As[srow * ALD + scol + 8] = *(const uint4*)(gA + kk + 8);
#pragma unroll
            for (int z = 0; z < 3; z++) {
                *(uint4*)&Bs[z * 64 * ALD + srow * ALD + scol]     = *(const uint4*)(gB + (size_t)z * 262144 + kk);
                *(uint4*)&Bs[z * 64 * ALD + srow * ALD + scol + 8] = *(const uint4*)(gB + (size_t)z * 262144 + kk + 8);
            }
            __syncthreads();

            short8 a[2][2];
#pragma unroll
            for (int i = 0; i < 2; i++)
#pragma unroll
                for (int kh = 0; kh < 2; kh++)
                    a[i][kh] = *(const short8*)&As[(wm + i * 16 + fr) * ALD + kh * 32 + fk];
#pragma unroll
            for (int z = 0; z < 3; z++) {
                short8 bf[2][2];
#pragma unroll
                for (int j = 0; j < 2; j++)
#pragma unroll
                    for (int kh = 0; kh < 2; kh++)
                        bf[j][kh] = *(const short8*)&Bs[z * 64 * ALD + (wn + j * 16 + fr) * ALD + kh * 32 + fk];
#pragma unroll
                for (int kh = 0; kh < 2; kh++)
#pragma unroll
                    for (int i = 0; i < 2; i++)
#pragma unroll
                        for (int j = 0; j < 2; j++)
                            acc[z][i][j] = __builtin_amdgcn_mfma_f32_16x16x32_bf16(a[i][kh], bf[j][kh], acc[z][i][j], 0, 0, 0);
            }
            __syncthreads();
        }

        // epilogue per z through LDS transpose tile (alias As)
        unsigned short* Tl = As;
        const int tr = t >> 2, tc = (t & 3) * 16;
#pragma unroll
        for (int z = 0; z < 3; z++) {
            if (z) __syncthreads();
            if (z < 2) {
#pragma unroll
                for (int i = 0; i < 2; i++)
#pragma unroll
                    for (int j = 0; j < 2; j++)
#pragma unroll
                        for (int r = 0; r < 4; r++)
                            Tl[(wm + i * 16 + fq * 4 + r) * ALD + wn + j * 16 + fr] =
                                f2bf(acc[z][i][j][r] + bv_[z][j]);
            } else {
#pragma unroll
                for (int i = 0; i < 2; i++)
#pragma unroll
                    for (int j = 0; j < 2; j++)
#pragma unroll
                        for (int r = 0; r < 4; r++)
                            Tl[(wn + j * 16 + fr) * ALD + wm + i * 16 + fq * 4 + r] =
                                f2bf(acc[z][i][j][r] + bv_[z][j]);
            }
            __syncthreads();

            uint4 v0 = *(const uint4*)&Tl[tr * ALD + tc];
            uint4 v1 = *(const uint4*)&Tl[tr * ALD + tc + 8];
            if (z < 2) {
                unsigned short* o = (z == 0) ? qb : kb;
                size_t off = (size_t)(m0 + tr) * 512 + n0 + tc;
                *(uint4*)&o[off]     = v0;
                *(uint4*)&o[off + 8] = v1;
            } else {
                size_t off = (size_t)(n0 + tr) * 4096 + m0 + tc;
                *(uint4*)&vt[off]     = v0;
                *(uint4*)&vt[off + 8] = v1;
            }
        }
    }
    gbar(cnt, 2 * NBLK);

    // ===================== Phase C: fused attention, 512 (Qt,b,eh) jobs ========
    // XCD-chunked decode: xcd = bid&7 owns 16 consecutive Q-tiles (K/V window
    // ~0.8 MB per XCD -> L2 hits).  4 waves: wave w computes score n-tiles
    // {w, w+4, (w==0: 8)}; one barrier; per-wave redundant softmax; wave w runs
    // PV for E-cols eh*256 + [64w, 64w+64).  Math identical to the validated
    // R3 kernel (loads clamped+batched, value-masking via -1e30 -> P=0).
    {
        float* Sl = (float*)lds_raw;   // 16 x SLD fp32

        const int g   = bid >> 3, xcd = bid & 7;
        const int Qt  = xcd * 16 + (g & 15);
        const int eh  = (g >> 4) & 1;
        const int b   = g >> 5;
        const int w = t >> 6, l = t & 63;
        const int fr = l & 15, fq = l >> 4;
        const int Q0 = Qt * 16;
        const int R0 = Q0 - WIN;

        // ---- scores
        {
            const unsigned short* qrow = qb + (size_t)(b * L_SEQ + Q0 + fr) * 512 + fq * 8;
            short8 qf[16];
#pragma unroll
            for (int ks = 0; ks < 16; ks++) qf[ks] = *(const short8*)(qrow + ks * 32);

            for (int nt = w; nt < 9; nt += 4) {
                const int tok = R0 + nt * 16 + fr;
                const bool kvalid = (tok >= 0) && (tok < L_SEQ);
                const int tokc = min(max(tok, 0), L_SEQ - 1);
                const unsigned short* krow = kb + (size_t)(b * L_SEQ + tokc) * 512 + fq * 8;

                floatx4 acc0 = {}, acc1 = {};
                short8 bfr[8];
#pragma unroll
                for (int ks = 0; ks < 8; ks++) bfr[ks] = *(const short8*)(krow + ks * 32);
#pragma unroll
                for (int ks = 0; ks < 8; ks++)
                    acc0 = __builtin_amdgcn_mfma_f32_16x16x32_bf16(qf[ks], bfr[ks], acc0, 0, 0, 0);
#pragma unroll
                for (int ks = 0; ks < 8; ks++) bfr[ks] = *(const short8*)(krow + (8 + ks) * 32);
#pragma unroll
                for (int ks = 0; ks < 8; ks++)
                    acc1 = __builtin_amdgcn_mfma_f32_16x16x32_bf16(qf[8 + ks], bfr[ks], acc1, 0, 0, 0);

                const int jg = nt * 16 + fr;
#pragma unroll
                for (int r = 0; r < 4; r++) {
                    int qq = fq * 4 + r;
                    bool valid = kvalid && (jg >= qq) && (jg <= qq + 128);
                    Sl[qq * SLD + jg] = valid ? (acc0[r] + acc1[r]) * SCALE_QK : -1e30f;
                }
            }
        }
        __syncthreads();

        // ---- softmax (per-wave redundant)
        const float* Srow = &Sl[fr * SLD + fq * 8];
        float sv[5][8];
#pragma unroll
        for (int ks = 0; ks < 5; ks++) {
            float4 u0 = *(const float4*)(Srow + ks * 32);
            float4 u1 = *(const float4*)(Srow + ks * 32 + 4);
            sv[ks][0] = u0.x; sv[ks][1] = u0.y; sv[ks][2] = u0.z; sv[ks][3] = u0.w;
            sv[ks][4] = u1.x; sv[ks][5] = u1.y; sv[ks][6] = u1.z; sv[ks][7] = u1.w;
        }
        if (fq >= 2) {
#pragma unroll
            for (int j = 0; j < 8; j++) sv[4][j] = -1e30f;
        }
        float m = -1e30f;
#pragma unroll
        for (int ks = 0; ks < 5; ks++)
#pragma unroll
            for (int j = 0; j < 8; j++) m = fmaxf(m, sv[ks][j]);
        m = fmaxf(m, __shfl_xor(m, 16));
        m = fmaxf(m, __shfl_xor(m, 32));
        float sum = 0.f;
#pragma unroll
        for (int ks = 0; ks < 5; ks++)
#pragma unroll
            for (int j = 0; j < 8; j++) { float e = __expf(sv[ks][j] - m); sv[ks][j] = e; sum += e; }
        sum += __shfl_xor(sum, 16);
        sum += __shfl_xor(sum, 32);
        float inv = 1.f / sum;

        short8 a[5];
#pragma unroll
        for (int ks = 0; ks < 5; ks++)
#pragma unroll
            for (int j = 0; j < 8; j++) a[ks][j] = (short)f2bf(sv[ks][j] * inv);

        // ---- PV: wave w owns E-cols eh*256 + [64w, 64w+64)
        const int EC = eh * 256 + w * 64;
        int tkc[5];
#pragma unroll
        for (int ks = 0; ks < 5; ks++) {
            int tok0 = R0 + ks * 32 + fq * 8;
            tkc[ks] = min(max(tok0, 0), L_SEQ - 8);
        }
        floatx4 oa[4] = {};
#pragma unroll
        for (int et = 0; et < 4; et++) {
            const unsigned short* vrow = vt + (size_t)(EC + et * 16 + fr) * 4096 + b * L_SEQ;
            short8 vfr[5];
#pragma unroll
            for (int ks = 0; ks < 5; ks++) vfr[ks] = *(const short8*)(vrow + tkc[ks]);
#pragma unroll
            for (int ks = 0; ks < 5; ks++)
                oa[et] = __builtin_amdgcn_mfma_f32_16x16x32_bf16(a[ks], vfr[ks], oa[et], 0, 0, 0);
        }

        float* op = out + (size_t)b * L_SEQ * E_DIM;
#pragma unroll
        for (int et = 0; et < 4; et++)
#pragma unroll
            for (int r = 0; r < 4; r++)
                op[(size_t)(Q0 + fq * 4 + r) * 512 + EC + et * 16 + fr] = oa[et][r];
    }
}

// ---------------- launch ----------------
extern "C" void kernel_launch(void* const* d_in, const int* in_sizes, int n_in,
                              void* d_out, int out_size, void* d_ws, size_t ws_size,
                              hipStream_t stream)
{
    const float* x  = (const float*)d_in[0];
    const float* Wq = (const float*)d_in[1];
    const float* bq = (const float*)d_in[2];
    const float* Wk = (const float*)d_in[3];
    const float* bk = (const float*)d_in[4];
    const float* Wv = (const float*)d_in[5];
    const float* bv = (const float*)d_in[6];
    float* out = (float*)d_out;

    char* ws = (char*)d_ws;
    unsigned short* qb = (unsigned short*)(ws);                  // 4 MB bf16 q
    unsigned short* kb = (unsigned short*)(ws + 4194304);        // 4 MB bf16 k
    unsigned short* vt = (unsigned short*)(ws + 8388608);        // 4 MB bf16 v^T [e][tok]
    unsigned short* xb = (unsigned short*)(ws + 12582912);       // 4 MB bf16 x
    unsigned short* wb = (unsigned short*)(ws + 16777216);       // 1.5 MB bf16 W
    unsigned int*  cnt = (unsigned int*)(ws + 33554432);         // barrier counter

    hipMemsetAsync(cnt, 0, 64, stream);                          // capturable memset node
    mega<<<NBLK, NTHR, 0, stream>>>(x, Wq, bq, Wk, bk, Wv, bv, out,
                                    xb, wb, qb, kb, vt, cnt);
}